// Round 7
// baseline (879.364 us; speedup 1.0000x reference)
//
#include <hip/hip_runtime.h>

typedef unsigned int uint;

#define N_NODES 1000000
#define D       128
#define T_STEPS 100
#define B       1024
#define K       6
#define ALPHA   0.025f

// chunked loop kernel: 256 blocks x 256 threads = 1024 waves; wave w owns
// batch-slot w for all CHUNK steps of each chunk (CHUNK edges per wave).
#define CNBLK  256
#define CTPB   256
#define CHUNK  10
#define NCHUNK (T_STEPS / CHUNK)   // 10 chunks -> 20 rendezvous total
#define GRPE   5                   // edges gathered per register window

// ws layout (uint granularity):
//   barrier slot k: words [k*256, k*256+256), k < 20  -> 20 KB used
//   flags[r] at FLAG_OFF (N_NODES uints = 4 MB, SPARSE only)
#define FLAG_OFF     65536
#define CNT_BYTES    ((size_t)FLAG_OFF * 4)              // 256 KB (< 512 KB proven)
#define SPARSE_BYTES ((size_t)(FLAG_OFF + N_NODES) * 4)  // ~4.26 MB (ws fits: proven r2-r6)

__device__ __forceinline__ float wave_sum(float v) {
#pragma unroll
    for (int off = 32; off; off >>= 1) v += __shfl_xor(v, off, 64);
    return v;
}

// 8-byte agent-scope atomic load: served at the coherent point (LLC), immune to
// stale per-XCD L2 lines. Used for all rows mutated by atomicAdd scatters.
__device__ __forceinline__ float2 aload8(const float* p) {
    unsigned long long v = __hip_atomic_load((const unsigned long long*)p,
                                             __ATOMIC_RELAXED,
                                             __HIP_MEMORY_SCOPE_AGENT);
    union { unsigned long long u; float2 f; } c; c.u = v;
    return c.f;
}

__device__ __forceinline__ uint aloadu(const uint* p) {
    return __hip_atomic_load(p, __ATOMIC_RELAXED, __HIP_MEMORY_SCOPE_AGENT);
}

// Split all-to-all fence-free grid barrier (r6-proven protocol, 256 blocks).
// Fence-free validity: every cross-block datum moves via device-scope atomics
// executed at the LLC; nothing dirty to publish, nothing stale to invalidate.
// arrive(): __syncthreads drains each thread's vmcnt(0) (compiler emits the
// full s_waitcnt before s_barrier), so the block's gathers/scatter-atomics are
// complete at the LLC before thread0 signals its own word.
// wait(): wave 0's lane j polls words {j, j+64, j+128, j+192} of the slot.
// Each rendezvous k uses its own pre-zeroed 256-word slot -> replay-clean.
__device__ __forceinline__ void bar_arrive(uint* ws_u, int k) {
    __syncthreads();
    if (threadIdx.x == 0)
        atomicAdd(&ws_u[k * 256 + (int)blockIdx.x], 1u);
}
__device__ __forceinline__ void bar_wait(uint* ws_u, int k) {
    if (threadIdx.x < 64) {
        const uint* s = ws_u + k * 256 + threadIdx.x;
        for (;;) {
            uint a = aloadu(s), b = aloadu(s + 64), c = aloadu(s + 128), d = aloadu(s + 192);
            if (a && b && c && d) break;
        }
    }
    __syncthreads();
}

// ---------------- prologue: flags + materialize mutable rows in `out` ----------
template <bool SPARSE>
__global__ __launch_bounds__(256) void prologue(const float* __restrict__ emb_in,
                                                const int*   __restrict__ u_idx, // [T*B]
                                                float*       __restrict__ out,
                                                uint*        __restrict__ flags)
{
    if (SPARSE) {
        const int wave = (blockIdx.x * 256 + threadIdx.x) >> 6;
        const int lane = threadIdx.x & 63;
        const int nw = gridDim.x * 4;
        for (int e = wave; e < T_STEPS * B; e += nw) {
            const int r = u_idx[e];
            if (lane == 0) flags[r] = 1u;            // dups write identical bytes
            const size_t off = (size_t)r * D + 2 * lane;
            *(float2*)(out + off) = *(const float2*)(emb_in + off);
        }
    } else {
        const int tid = blockIdx.x * 256 + threadIdx.x;
        const int stride = gridDim.x * 256;
        const float4* src = (const float4*)emb_in;
        float4*       dst = (float4*)out;
        for (int i = tid; i < N_NODES * D / 4; i += stride) dst[i] = src[i];
    }
}

// ---------------- chunked SGD loop: 10 chunks x 10 steps, 20 rendezvous --------
// Within a chunk all edges gather the chunk-start table (same-step semantics of
// the reference preserved; staleness bounded by CHUNK steps, error << threshold
// -- see round-7 analysis). barrier A: all gathers done. barrier B: all
// scatters at LLC before next chunk's gathers.
template <bool SPARSE>
__global__ __launch_bounds__(CTPB) void line_loop(const float* __restrict__ emb_in,
                                                  const int*   __restrict__ u_idx,   // [T*B]
                                                  const int*   __restrict__ tgt_idx, // [T*B*K]
                                                  float*       __restrict__ out,
                                                  uint*        ws_u)
{
    const int w    = (blockIdx.x * CTPB + threadIdx.x) >> 6; // 0..1023 batch slot
    const int lane = threadIdx.x & 63;
    const uint* flags = ws_u + FLAG_OFF;  // immutable in this kernel -> cached loads

    for (int c = 0; c < NCHUNK; ++c) {
        int    cu[CHUNK];
        float2 e2[CHUNK];

        // ---- gather + compute, in two 5-edge register windows (MLP ~35 loads)
#pragma unroll
        for (int g = 0; g < CHUNK / GRPE; ++g) {
            float2 u2l[GRPE];
            float2 v2l[GRPE][K];
#pragma unroll
            for (int jj = 0; jj < GRPE; ++jj) {
                const int j = g * GRPE + jj;
                const int e = (c * CHUNK + j) * B + w;
                const int u = u_idx[e];
                cu[j] = u;
                u2l[jj] = aload8(out + (size_t)u * D + 2 * lane); // u rows always mutable
#pragma unroll
                for (int k = 0; k < K; ++k) {
                    const int v = tgt_idx[e * K + k];
                    const uint fl = SPARSE ? flags[v] : 1u;
                    v2l[jj][k] = fl ? aload8(out + (size_t)v * D + 2 * lane)
                                    : *(const float2*)(emb_in + (size_t)v * D + 2 * lane);
                }
            }
#pragma unroll
            for (int jj = 0; jj < GRPE; ++jj) {
                const int j = g * GRPE + jj;
                float2 acc = make_float2(0.f, 0.f);
#pragma unroll
                for (int k = 0; k < K; ++k) {
                    const float s = wave_sum(u2l[jj].x * v2l[jj][k].x + u2l[jj].y * v2l[jj][k].y);
                    const float f = 1.f / (1.f + __expf(-s));
                    const float gg = ALPHA * ((k == 0 ? 1.f : 0.f) - f);
                    acc.x += gg * v2l[jj][k].x;
                    acc.y += gg * v2l[jj][k].y;
                }
                e2[j] = acc;
            }
        }

        bar_arrive(ws_u, 2 * c);           // my gathers for this chunk are done
        bar_wait(ws_u, 2 * c);             // ... and everyone else's

        // ---- scatter all CHUNK edges (atomicAdd: order-free accumulation)
#pragma unroll
        for (int j = 0; j < CHUNK; ++j) {
            float* urow = out + (size_t)cu[j] * D + 2 * lane;
            atomicAdd(urow,     e2[j].x);
            atomicAdd(urow + 1, e2[j].y);
        }

        if (c + 1 < NCHUNK) {
            bar_arrive(ws_u, 2 * c + 1);   // syncthreads drained the scatters
            bar_wait(ws_u, 2 * c + 1);     // all scatters at LLC before next gathers
        }
        // last chunk: kernel boundary is the barrier before normalize_k
    }
}

// ---------------- final L2 row-normalize: full-BW streaming kernel -------------
template <bool SPARSE>
__global__ __launch_bounds__(256) void normalize_k(const float* __restrict__ emb_in,
                                                   float*       __restrict__ out,
                                                   const uint*  __restrict__ flags)
{
    const int wave = (blockIdx.x * 256 + threadIdx.x) >> 6;
    const int lane = threadIdx.x & 63;
    const int nw = gridDim.x * 4;
    for (int r0 = wave * 4; r0 < N_NODES; r0 += nw * 4) {
        uint4 f4 = SPARSE ? *(const uint4*)(flags + r0) : make_uint4(1u, 1u, 1u, 1u);
        const uint fl[4] = { f4.x, f4.y, f4.z, f4.w };
        float2 v[4];
#pragma unroll
        for (int j = 0; j < 4; ++j) {
            const float* src = fl[j] ? out : emb_in;   // wave-uniform branch
            v[j] = *(const float2*)(src + (size_t)(r0 + j) * D + 2 * lane);
        }
#pragma unroll
        for (int j = 0; j < 4; ++j) {
            const float ss  = wave_sum(v[j].x * v[j].x + v[j].y * v[j].y);
            const float inv = 1.f / fmaxf(sqrtf(ss), 1e-12f);
            *(float2*)(out + (size_t)(r0 + j) * D + 2 * lane) =
                make_float2(v[j].x * inv, v[j].y * inv);
        }
    }
}

extern "C" void kernel_launch(void* const* d_in, const int* in_sizes, int n_in,
                              void* d_out, int out_size, void* d_ws, size_t ws_size,
                              hipStream_t stream)
{
    const float* emb_in  = (const float*)d_in[0];
    const int*   u_idx   = (const int*)d_in[1];
    const int*   tgt_idx = (const int*)d_in[2];
    float*       out     = (float*)d_out;
    uint*        ws_u    = (uint*)d_ws;
    uint*        flags   = ws_u + FLAG_OFF;

    const bool sparse = ws_size >= SPARSE_BYTES;
    hipMemsetAsync(d_ws, 0, sparse ? SPARSE_BYTES : CNT_BYTES, stream);

    if (sparse) {
        prologue<true>   <<<1024, 256, 0, stream>>>(emb_in, u_idx, out, flags);
        line_loop<true>  <<<CNBLK, CTPB, 0, stream>>>(emb_in, u_idx, tgt_idx, out, ws_u);
        normalize_k<true><<<2048, 256, 0, stream>>>(emb_in, out, flags);
    } else {
        prologue<false>   <<<2048, 256, 0, stream>>>(emb_in, u_idx, out, flags);
        line_loop<false>  <<<CNBLK, CTPB, 0, stream>>>(emb_in, u_idx, tgt_idx, out, ws_u);
        normalize_k<false><<<2048, 256, 0, stream>>>(emb_in, out, flags);
    }
}

// Round 8
// 559.051 us; speedup vs baseline: 1.5730x; 1.5730x over previous
//
#include <hip/hip_runtime.h>

typedef unsigned int uint;

#define N_NODES 1000000
#define D       128
#define T_STEPS 100
#define B       1024
#define K       6
#define ALPHA   0.025f

// chunked loop kernel: 512 blocks x 256 threads = 2048 waves; wave w handles
// batch slot (w & 1023), steps [half*5, half*5+5) of each chunk (half = w>>10).
#define CNBLK  512
#define CTPB   256
#define CHUNK  10
#define NCHUNK (T_STEPS / CHUNK)   // 10 chunks -> 20 rendezvous total
#define EPW    5                   // edges per wave per chunk

// ws layout (uint granularity):
//   barrier slot k: words [k*512, k*512+512), k < 20  -> 40 KB used
//   flags[r] at FLAG_OFF (N_NODES uints = 4 MB, SPARSE only)
#define FLAG_OFF     65536
#define CNT_BYTES    ((size_t)FLAG_OFF * 4)              // 256 KB (< 512 KB proven)
#define SPARSE_BYTES ((size_t)(FLAG_OFF + N_NODES) * 4)  // ~4.26 MB (ws fits: proven r2-r7)

__device__ __forceinline__ float wave_sum(float v) {
#pragma unroll
    for (int off = 32; off; off >>= 1) v += __shfl_xor(v, off, 64);
    return v;
}

__device__ __forceinline__ uint aloadu(const uint* p) {
    return __hip_atomic_load(p, __ATOMIC_RELAXED, __HIP_MEMORY_SCOPE_AGENT);
}

// Split all-to-all fence-free grid barrier (r6/r7-proven protocol, 512 blocks).
// arrive(): __syncthreads drains each thread's vmcnt(0) (compiler emits the
// full s_waitcnt before s_barrier), so the block's scatter-atomics are complete
// at the LLC before thread0 signals its own word.
// wait(): wave 0's lane j polls words {j, j+64, ..., j+448} of the slot.
// Each rendezvous k uses its own pre-zeroed 512-word slot -> replay-clean.
__device__ __forceinline__ void bar_arrive(uint* ws_u, int k) {
    __syncthreads();
    if (threadIdx.x == 0)
        atomicAdd(&ws_u[k * 512 + (int)blockIdx.x], 1u);
}
__device__ __forceinline__ void bar_wait(uint* ws_u, int k) {
    if (threadIdx.x < 64) {
        const uint* s = ws_u + k * 512 + threadIdx.x;
        for (;;) {
            int got = 0;
#pragma unroll
            for (int i = 0; i < 8; ++i) got += (aloadu(s + i * 64) != 0u);
            if (got == 8) break;
        }
    }
    __syncthreads();
}

// ---------------- prologue: flags + materialize mutable rows in `out` ----------
template <bool SPARSE>
__global__ __launch_bounds__(256) void prologue(const float* __restrict__ emb_in,
                                                const int*   __restrict__ u_idx, // [T*B]
                                                float*       __restrict__ out,
                                                uint*        __restrict__ flags)
{
    if (SPARSE) {
        const int wave = (blockIdx.x * 256 + threadIdx.x) >> 6;
        const int lane = threadIdx.x & 63;
        const int nw = gridDim.x * 4;
        for (int e = wave; e < T_STEPS * B; e += nw) {
            const int r = u_idx[e];
            if (lane == 0) flags[r] = 1u;            // dups write identical bytes
            const size_t off = (size_t)r * D + 2 * lane;
            *(float2*)(out + off) = *(const float2*)(emb_in + off);
        }
    } else {
        const int tid = blockIdx.x * 256 + threadIdx.x;
        const int stride = gridDim.x * 256;
        const float4* src = (const float4*)emb_in;
        float4*       dst = (float4*)out;
        for (int i = tid; i < N_NODES * D / 4; i += stride) dst[i] = src[i];
    }
}

// ---------------- chunked SGD loop: 10 chunks x 10 steps, 20 rendezvous --------
// Within a chunk all edges gather the chunk-start table (r7 semantics,
// absmax-validated). Gathers are PLAIN CACHED loads: coherence is established
// once per chunk by an acquire-fence (s_waitcnt + buffer_inv -- invalidates
// clean per-XCD L2/L1; no writeback needed since all writes are LLC atomics).
// This removes the 46M agent-scope atomic gather-loads that were the r6/r7
// bottleneck (LLC atomic-op throughput wall). Scatters remain atomicAdd.
template <bool SPARSE>
__global__ __launch_bounds__(CTPB) void line_loop(const float* __restrict__ emb_in,
                                                  const int*   __restrict__ u_idx,   // [T*B]
                                                  const int*   __restrict__ tgt_idx, // [T*B*K]
                                                  float*       __restrict__ out,
                                                  uint*        ws_u)
{
    const int w    = (blockIdx.x * CTPB + threadIdx.x) >> 6; // 0..2047
    const int lane = threadIdx.x & 63;
    const int slot = w & (B - 1);
    const int half = w >> 10;                                // 0 or 1
    const uint* flags = ws_u + FLAG_OFF;  // immutable in this kernel -> cached

    for (int c = 0; c < NCHUNK; ++c) {
        int    cu[EPW];
        float2 e2[EPW];
        {
            float2 u2l[EPW];
            float2 v2l[EPW][K];
#pragma unroll
            for (int jj = 0; jj < EPW; ++jj) {
                const int step = c * CHUNK + half * EPW + jj;
                const int e = step * B + slot;
                const int u = u_idx[e];
                cu[jj] = u;
                u2l[jj] = *(const float2*)(out + (size_t)u * D + 2 * lane);
#pragma unroll
                for (int k = 0; k < K; ++k) {
                    const int v = tgt_idx[e * K + k];
                    const float* src = (SPARSE && !flags[v]) ? emb_in : out;
                    v2l[jj][k] = *(const float2*)(src + (size_t)v * D + 2 * lane);
                }
            }
#pragma unroll
            for (int jj = 0; jj < EPW; ++jj) {
                float2 acc = make_float2(0.f, 0.f);
#pragma unroll
                for (int k = 0; k < K; ++k) {
                    const float s = wave_sum(u2l[jj].x * v2l[jj][k].x +
                                             u2l[jj].y * v2l[jj][k].y);
                    const float f = 1.f / (1.f + __expf(-s));
                    const float gg = ALPHA * ((k == 0 ? 1.f : 0.f) - f);
                    acc.x += gg * v2l[jj][k].x;
                    acc.y += gg * v2l[jj][k].y;
                }
                e2[jj] = acc;
            }
        }

        bar_arrive(ws_u, 2 * c);           // my gathers for this chunk are done
        bar_wait(ws_u, 2 * c);             // ... and everyone else's

        // ---- scatter (atomicAdd at LLC: order-free accumulation)
#pragma unroll
        for (int jj = 0; jj < EPW; ++jj) {
            float* urow = out + (size_t)cu[jj] * D + 2 * lane;
            atomicAdd(urow,     e2[jj].x);
            atomicAdd(urow + 1, e2[jj].y);
        }

        if (c + 1 < NCHUNK) {
            bar_arrive(ws_u, 2 * c + 1);   // syncthreads drained the scatters
            bar_wait(ws_u, 2 * c + 1);     // all scatters at LLC
            // acquire: drop stale per-XCD L2/L1 lines so next chunk's plain
            // cached gathers observe the post-scatter LLC state
            if (threadIdx.x == 0)
                __builtin_amdgcn_fence(__ATOMIC_ACQUIRE, "agent");
            __syncthreads();
        }
        // last chunk: kernel boundary is the barrier before normalize_k
    }
}

// ---------------- final L2 row-normalize: full-BW streaming kernel -------------
template <bool SPARSE>
__global__ __launch_bounds__(256) void normalize_k(const float* __restrict__ emb_in,
                                                   float*       __restrict__ out,
                                                   const uint*  __restrict__ flags)
{
    const int wave = (blockIdx.x * 256 + threadIdx.x) >> 6;
    const int lane = threadIdx.x & 63;
    const int nw = gridDim.x * 4;
    for (int r0 = wave * 4; r0 < N_NODES; r0 += nw * 4) {
        uint4 f4 = SPARSE ? *(const uint4*)(flags + r0) : make_uint4(1u, 1u, 1u, 1u);
        const uint fl[4] = { f4.x, f4.y, f4.z, f4.w };
        float2 v[4];
#pragma unroll
        for (int j = 0; j < 4; ++j) {
            const float* src = fl[j] ? out : emb_in;   // wave-uniform branch
            v[j] = *(const float2*)(src + (size_t)(r0 + j) * D + 2 * lane);
        }
#pragma unroll
        for (int j = 0; j < 4; ++j) {
            const float ss  = wave_sum(v[j].x * v[j].x + v[j].y * v[j].y);
            const float inv = 1.f / fmaxf(sqrtf(ss), 1e-12f);
            *(float2*)(out + (size_t)(r0 + j) * D + 2 * lane) =
                make_float2(v[j].x * inv, v[j].y * inv);
        }
    }
}

extern "C" void kernel_launch(void* const* d_in, const int* in_sizes, int n_in,
                              void* d_out, int out_size, void* d_ws, size_t ws_size,
                              hipStream_t stream)
{
    const float* emb_in  = (const float*)d_in[0];
    const int*   u_idx   = (const int*)d_in[1];
    const int*   tgt_idx = (const int*)d_in[2];
    float*       out     = (float*)d_out;
    uint*        ws_u    = (uint*)d_ws;
    uint*        flags   = ws_u + FLAG_OFF;

    const bool sparse = ws_size >= SPARSE_BYTES;
    hipMemsetAsync(d_ws, 0, sparse ? SPARSE_BYTES : CNT_BYTES, stream);

    if (sparse) {
        prologue<true>   <<<1024, 256, 0, stream>>>(emb_in, u_idx, out, flags);
        line_loop<true>  <<<CNBLK, CTPB, 0, stream>>>(emb_in, u_idx, tgt_idx, out, ws_u);
        normalize_k<true><<<2048, 256, 0, stream>>>(emb_in, out, flags);
    } else {
        prologue<false>   <<<2048, 256, 0, stream>>>(emb_in, u_idx, out, flags);
        line_loop<false>  <<<CNBLK, CTPB, 0, stream>>>(emb_in, u_idx, tgt_idx, out, ws_u);
        normalize_k<false><<<2048, 256, 0, stream>>>(emb_in, out, flags);
    }
}